// Round 1
// baseline (178.989 us; speedup 1.0000x reference)
//
#include <hip/hip_runtime.h>

typedef _Float16 half2_t __attribute__((ext_vector_type(2)));
typedef float float4_t __attribute__((ext_vector_type(4)));

#define U_PAR 0.45f
#define A_STD 0.006667f
#define A_STF 0.05f
#define DT_S  0.01f

#define T_STEPS 64
#define BATCH   16
#define NIN     64
#define NH      256
#define NOUT    16

// d_out layout (floats): h_all (65,16,256) | y (64,16,16) | sx_all (65,16,256,256) | su_all (...)
#define H_OFF  0
#define H_SZ   ((T_STEPS + 1) * BATCH * NH)            // 266240
#define Y_OFF  H_SZ
#define Y_SZ   (T_STEPS * BATCH * NOUT)                // 16384
#define SX_OFF (Y_OFF + Y_SZ)                          // 282624
#define PLANE  ((T_STEPS + 1) * BATCH * NH)            // rows per big array = 266240
#define SX_SZ  ((size_t)PLANE * NH)
#define SU_OFF ((size_t)SX_OFF + SX_SZ)

static __device__ __forceinline__ float fdot2f(half2_t a, half2_t b, float c) {
#if __has_builtin(__builtin_amdgcn_fdot2)
  return __builtin_amdgcn_fdot2(a, b, c, false);
#else
  return c + (float)a.x * (float)b.x + (float)a.y * (float)b.y;
#endif
}

// ---------------- Phase 1: per-batch sequential recurrence -------------------
// 16 blocks (one per batch), 512 threads: j = tid&255 (output column),
// q = tid>>8 (K-half). W_rec column j, rows [q*128, q*128+128) lives in regs
// as 64 half2. q==1 threads additionally hold W_in column j (32 half2) and
// compute xw = x @ W_in each step.
__global__ __launch_bounds__(512) void rnn_phase1(
    const float* __restrict__ x, const float* __restrict__ Win,
    const float* __restrict__ Wrec, const float* __restrict__ Wbias,
    float* __restrict__ out)
{
  const int b   = blockIdx.x;
  const int tid = threadIdx.x;
  const int j   = tid & 255;
  const int q   = tid >> 8;   // 0 or 1

  __shared__ __align__(16) _Float16 g_h[NH];
  __shared__ __align__(16) _Float16 x_h[NIN];
  __shared__ float p_s[NH];
  __shared__ float xw_s[NH];
  __shared__ float red_s[8];

  // one-time: load W_rec fragment into registers (coalesced over j)
  half2_t w2[64];
#pragma unroll
  for (int k = 0; k < 64; ++k) {
    float a0 = Wrec[(q * 128 + 2 * k) * NH + j];
    float a1 = Wrec[(q * 128 + 2 * k + 1) * NH + j];
    half2_t v; v.x = (_Float16)a0; v.y = (_Float16)a1;
    w2[k] = v;
  }
  half2_t win2[32];
  if (q == 1) {
#pragma unroll
    for (int k = 0; k < 32; ++k) {
      float a0 = Win[(2 * k) * NH + j];
      float a1 = Win[(2 * k + 1) * NH + j];
      half2_t v; v.x = (_Float16)a0; v.y = (_Float16)a1;
      win2[k] = v;
    }
  }

  float h = 0.f, sx = 1.f, su = U_PAR;   // su0 = U_std + 1 = 0.45
  float bias = 0.f;
  if (q == 0) bias = Wbias[j];

  // t = 0 outputs: h_all[0] = 0, compact sx/su initial values at elem0 of each row
  if (q == 0) {
    out[H_OFF + b * NH + j] = 0.f;
    size_t row0 = (size_t)(0 * BATCH + b) * NH + j;
    out[SX_OFF + row0 * NH] = 1.f;
    out[SU_OFF + row0 * NH] = U_PAR;
  }

  for (int t = 0; t < T_STEPS; ++t) {
    // (a) q0: wave-reduce h for S; q1: stage x[t,b,:] as fp16
    if (q == 0) {
      float s = h;
#pragma unroll
      for (int m = 1; m < 64; m <<= 1) s += __shfl_xor(s, m, 64);
      if ((tid & 63) == 0) red_s[tid >> 6] = s;
    } else {
      if (j < NIN) x_h[j] = (_Float16)x[(size_t)(t * BATCH + b) * NIN + j];
    }
    __syncthreads();  // B1: red_s, x_h visible

    float partial = 0.f;
    if (q == 0) {
      float S   = red_s[0] + red_s[1] + red_s[2] + red_s[3];
      float sxn = sx + A_STD * (1.f - sx) - DT_S * su * sx * h;
      float v   = U_PAR * (1.f - su) * S;
      float sun = su + A_STF * (U_PAR - su) + DT_S * v;
      sxn = fminf(fmaxf(sxn, 0.f), 1.f);
      sun = fminf(fmaxf(sun, 0.f), 1.f);
      float g = h * sxn * sun;
      g_h[j] = (_Float16)g;
      sx = sxn; su = sun;
      size_t row = (size_t)((t + 1) * BATCH + b) * NH + j;   // compact outputs
      out[SX_OFF + row * NH] = sxn;
      out[SU_OFF + row * NH] = sun;
    } else {
      float xw = 0.f;
      const half2_t* x2 = (const half2_t*)x_h;
#pragma unroll
      for (int k = 0; k < 32; ++k) xw = fdot2f(win2[k], x2[k], xw);
      xw_s[j] = xw;
    }
    __syncthreads();  // B2: g_h, xw_s visible

    {
      const half2_t* g2 = (const half2_t*)g_h;
#pragma unroll
      for (int k = 0; k < 64; ++k) partial = fdot2f(w2[k], g2[q * 64 + k], partial);
    }
    if (q == 1) p_s[j] = partial;
    __syncthreads();  // B3: p_s visible

    if (q == 0) {
      float rec = partial + p_s[j];
      float hn  = 0.9f * h + 0.1f * (rec + bias) + xw_s[j];
      hn = fmaxf(hn, 0.f);
      out[H_OFF + ((size_t)(t + 1) * BATCH + b) * NH + j] = hn;
      h = hn;
    }
  }
}

// ---------------- Phase 1b: output head y = sigmoid(h @ W_out + b) -----------
__global__ __launch_bounds__(256) void rnn_yhead(
    const float* __restrict__ Wout, const float* __restrict__ Woutb,
    float* __restrict__ out)
{
  const int tb = blockIdx.x;                 // t*BATCH + b
  const int t  = tb / BATCH, b = tb % BATCH;
  const int j  = threadIdx.x;
  __shared__ float red[NOUT][5];

  float h = out[H_OFF + ((size_t)(t + 1) * BATCH + b) * NH + j];
  const float* wrow = Wout + j * NOUT;       // contiguous 16 floats per thread
#pragma unroll
  for (int o = 0; o < NOUT; ++o) {
    float v = h * wrow[o];
#pragma unroll
    for (int m = 1; m < 64; m <<= 1) v += __shfl_xor(v, m, 64);
    if ((j & 63) == 0) red[o][j >> 6] = v;
  }
  __syncthreads();
  if (j < NOUT) {
    float v = red[j][0] + red[j][1] + red[j][2] + red[j][3] + Woutb[j];
    out[Y_OFF + (size_t)tb * NOUT + j] = 1.f / (1.f + expf(-v));
  }
}

// ---------------- Phase 2: broadcast compact rows to full (..,H,H) ----------
// Row r in [0, 2*PLANE): contiguous through sx_all then su_all. Each row's
// value sits at its elem0 (written by phase 1); broadcast to all 256 elems.
__global__ __launch_bounds__(256) void rnn_bcast(float* __restrict__ out)
{
  const size_t base = SX_OFF;
  const int ROWS = 32;
  __shared__ float sval[ROWS];
  const int ngroups = (2 * PLANE) / ROWS;    // 16640
  for (int grp = blockIdx.x; grp < ngroups; grp += gridDim.x) {
    size_t r0 = (size_t)grp * ROWS;
    if (threadIdx.x < ROWS) sval[threadIdx.x] = out[base + (r0 + threadIdx.x) * NH];
    __syncthreads();
#pragma unroll
    for (int p = 0; p < 8; ++p) {            // 32 rows * 64 f4 = 2048 f4
      int id = p * 256 + threadIdx.x;
      int r = id >> 6, c = id & 63;
      float v = sval[r];
      float4_t f4 = {v, v, v, v};
      float4_t* dst = (float4_t*)(out + base + (r0 + r) * NH);
      __builtin_nontemporal_store(f4, dst + c);
    }
    __syncthreads();
  }
}

extern "C" void kernel_launch(void* const* d_in, const int* in_sizes, int n_in,
                              void* d_out, int out_size, void* d_ws, size_t ws_size,
                              hipStream_t stream) {
  (void)in_sizes; (void)n_in; (void)d_ws; (void)ws_size; (void)out_size;
  const float* x     = (const float*)d_in[0];
  const float* Win   = (const float*)d_in[1];
  const float* Wrec  = (const float*)d_in[2];
  const float* Wbias = (const float*)d_in[3];
  const float* Wout  = (const float*)d_in[4];
  const float* Woutb = (const float*)d_in[5];
  float* out = (float*)d_out;

  hipLaunchKernelGGL(rnn_phase1, dim3(BATCH), dim3(512), 0, stream,
                     x, Win, Wrec, Wbias, out);
  hipLaunchKernelGGL(rnn_yhead, dim3(T_STEPS * BATCH), dim3(256), 0, stream,
                     Wout, Woutb, out);
  hipLaunchKernelGGL(rnn_bcast, dim3(2048), dim3(256), 0, stream, out);
}